// Round 5
// baseline (58.113 us; speedup 1.0000x reference)
//
#include <hip/hip_runtime.h>
#include <hip/hip_bf16.h>
#include <hip/hip_fp16.h>

// z[b,i] = mu[a_b, i] + sum_{j<=i} L[a_b, i, j] * eps[b, j]
// B = 1048576, A = 65536, D = 8
//
// Round-5: test the outstanding-miss hypothesis. Gathers go through
// global_load_lds (per-lane scattered source, zero VGPR cost) so each
// wave keeps 14 scattered vmem insts (~256 line reqs) in flight.
// 1-wave blocks, 2 groups of 64 rows, 14KB LDS -> 11 blocks/CU.

#define A_CNT 65536

typedef float    f32x4 __attribute__((ext_vector_type(4)));
typedef _Float16 f16x8 __attribute__((ext_vector_type(8)));

// Record layout (64 halfs = 128B):
//  ch0 = mu[0..7]
//  ch1 = L[0][0..3], L[1][0..3]
//  ch2 = L[2][0..3], L[3][0..3]
//  ch3..6 = L[4..7][0..7]
//  ch7 = pad (never read)
__global__ __launch_bounds__(256) void pack_kernel(
    const float* __restrict__ mu,   // [A,8]
    const float* __restrict__ L,    // [A,64]
    _Float16* __restrict__ rec,     // [A,64] halfs
    int A)
{
    int a = blockIdx.x * blockDim.x + threadIdx.x;
    if (a >= A) return;

    const f32x4* muv = reinterpret_cast<const f32x4*>(mu + (size_t)a * 8);
    const f32x4* Lv  = reinterpret_cast<const f32x4*>(L + (size_t)a * 64);
    f32x4 m0 = __builtin_nontemporal_load(muv);
    f32x4 m1 = __builtin_nontemporal_load(muv + 1);
    f32x4 r0 = __builtin_nontemporal_load(Lv + 0);
    f32x4 r1 = __builtin_nontemporal_load(Lv + 2);
    f32x4 r2 = __builtin_nontemporal_load(Lv + 4);
    f32x4 r3 = __builtin_nontemporal_load(Lv + 6);
    f32x4 r4a = __builtin_nontemporal_load(Lv + 8),  r4b = __builtin_nontemporal_load(Lv + 9);
    f32x4 r5a = __builtin_nontemporal_load(Lv + 10), r5b = __builtin_nontemporal_load(Lv + 11);
    f32x4 r6a = __builtin_nontemporal_load(Lv + 12), r6b = __builtin_nontemporal_load(Lv + 13);
    f32x4 r7a = __builtin_nontemporal_load(Lv + 14), r7b = __builtin_nontemporal_load(Lv + 15);

    f16x8 ch[8];
    #pragma unroll
    for (int j = 0; j < 4; ++j) {
        ch[0][j] = (_Float16)m0[j];  ch[0][4+j] = (_Float16)m1[j];
        ch[1][j] = (_Float16)r0[j];  ch[1][4+j] = (_Float16)r1[j];
        ch[2][j] = (_Float16)r2[j];  ch[2][4+j] = (_Float16)r3[j];
        ch[3][j] = (_Float16)r4a[j]; ch[3][4+j] = (_Float16)r4b[j];
        ch[4][j] = (_Float16)r5a[j]; ch[4][4+j] = (_Float16)r5b[j];
        ch[5][j] = (_Float16)r6a[j]; ch[5][4+j] = (_Float16)r6b[j];
        ch[6][j] = (_Float16)r7a[j]; ch[6][4+j] = (_Float16)r7b[j];
        ch[7][j] = (_Float16)0.f;    ch[7][4+j] = (_Float16)0.f;
    }
    f16x8* o = reinterpret_cast<f16x8*>(rec + (size_t)a * 64);
    #pragma unroll
    for (int c = 0; c < 8; ++c) __builtin_nontemporal_store(ch[c], o + c);
}

__device__ __forceinline__ void compute_row(const f16x8 ch[7], const float e[8],
                                            float z[8]) {
    #pragma unroll
    for (int i = 0; i < 8; ++i) z[i] = (float)ch[0][i];
    #pragma unroll
    for (int i = 0; i < 4; ++i) {
        #pragma unroll
        for (int j = 0; j <= i; ++j)
            z[i] += (float)ch[1 + (i >> 1)][(i & 1) * 4 + j] * e[j];
    }
    #pragma unroll
    for (int i = 4; i < 8; ++i) {
        #pragma unroll
        for (int j = 0; j <= i; ++j)
            z[i] += (float)ch[3 + (i - 4)][j] * e[j];
    }
}

__global__ __launch_bounds__(64) void lv_lds(
    const int* __restrict__ ann,          // [B]
    const _Float16* __restrict__ rec,     // [A,64] halfs, 128B/record
    const float* __restrict__ eps,        // [B,8]
    float* __restrict__ out,              // [B,8]
    int B)
{
    // one wave per block; 2 groups of 64 rows; LDS region per group:
    // chunk c of row r at c*1024 + r*16 (global_load_lds lands lane r's
    // 16B at uniform_base + lane*16). ds_read_b128 at lane*16 stride is
    // structurally bank-conflict-free.
    __shared__ __align__(16) char lds[2 * 7 * 1024];

    const int lane = threadIdx.x;                 // 0..63
    const long base = (long)blockIdx.x * 128;
    const long b0 = base + lane;
    const long b1 = base + 64 + lane;

    int a0 = 0, a1 = 0;
    if (b0 < (long)B) a0 = __builtin_nontemporal_load(ann + b0);
    if (b1 < (long)B) a1 = __builtin_nontemporal_load(ann + b1);

    const char* r0 = (const char*)rec + (size_t)a0 * 128;
    const char* r1 = (const char*)rec + (size_t)a1 * 128;

    // 14 scattered direct-to-LDS gathers in flight (no VGPR landing zone)
    #pragma unroll
    for (int c = 0; c < 7; ++c)
        __builtin_amdgcn_global_load_lds(
            (const __attribute__((address_space(1))) void*)(r0 + c * 16),
            (__attribute__((address_space(3))) void*)(lds + c * 1024),
            16, 0, 0);
    #pragma unroll
    for (int c = 0; c < 7; ++c)
        __builtin_amdgcn_global_load_lds(
            (const __attribute__((address_space(1))) void*)(r1 + c * 16),
            (__attribute__((address_space(3))) void*)(lds + 7168 + c * 1024),
            16, 0, 0);

    // eps for both groups (issued while gathers are in flight)
    const long bc0 = (b0 < (long)B) ? b0 : 0;
    const long bc1 = (b1 < (long)B) ? b1 : 0;
    const f32x4* e0p = reinterpret_cast<const f32x4*>(eps + (size_t)bc0 * 8);
    const f32x4* e1p = reinterpret_cast<const f32x4*>(eps + (size_t)bc1 * 8);
    const f32x4 e00 = __builtin_nontemporal_load(e0p);
    const f32x4 e01 = __builtin_nontemporal_load(e0p + 1);
    const f32x4 e10 = __builtin_nontemporal_load(e1p);
    const f32x4 e11 = __builtin_nontemporal_load(e1p + 1);

    // drain all vmem (incl. LDS-DMA) before consuming LDS
    asm volatile("s_waitcnt vmcnt(0)" ::: "memory");

    // ---- group 0 ----
    if (b0 < (long)B) {
        f16x8 ch[7];
        #pragma unroll
        for (int c = 0; c < 7; ++c)
            ch[c] = *reinterpret_cast<const f16x8*>(lds + c * 1024 + lane * 16);
        const float e[8] = {e00[0], e00[1], e00[2], e00[3],
                            e01[0], e01[1], e01[2], e01[3]};
        float z[8];
        compute_row(ch, e, z);
        f32x4* outv = reinterpret_cast<f32x4*>(out + (size_t)b0 * 8);
        f32x4 o0 = {z[0], z[1], z[2], z[3]};
        f32x4 o1 = {z[4], z[5], z[6], z[7]};
        __builtin_nontemporal_store(o0, outv);
        __builtin_nontemporal_store(o1, outv + 1);
    }
    // ---- group 1 ----
    if (b1 < (long)B) {
        f16x8 ch[7];
        #pragma unroll
        for (int c = 0; c < 7; ++c)
            ch[c] = *reinterpret_cast<const f16x8*>(lds + 7168 + c * 1024 + lane * 16);
        const float e[8] = {e10[0], e10[1], e10[2], e10[3],
                            e11[0], e11[1], e11[2], e11[3]};
        float z[8];
        compute_row(ch, e, z);
        f32x4* outv = reinterpret_cast<f32x4*>(out + (size_t)b1 * 8);
        f32x4 o0 = {z[0], z[1], z[2], z[3]};
        f32x4 o1 = {z[4], z[5], z[6], z[7]};
        __builtin_nontemporal_store(o0, outv);
        __builtin_nontemporal_store(o1, outv + 1);
    }
}

// ---- fallback: fp32 direct (if ws too small) ----
__global__ __launch_bounds__(256) void lv_kernel_f32(
    const int* __restrict__ ann,
    const float* __restrict__ mu,
    const float* __restrict__ L,
    const float* __restrict__ eps,
    float* __restrict__ out,
    int B)
{
    int b = blockIdx.x * blockDim.x + threadIdx.x;
    if (b >= B) return;
    const int a = ann[b];
    const f32x4* epsv = reinterpret_cast<const f32x4*>(eps + (size_t)b * 8);
    const f32x4 e0 = epsv[0];
    const f32x4 e1 = epsv[1];
    const float e[8] = {e0[0], e0[1], e0[2], e0[3], e1[0], e1[1], e1[2], e1[3]};
    const f32x4* muv = reinterpret_cast<const f32x4*>(mu + (size_t)a * 8);
    const f32x4 m0 = muv[0];
    const f32x4 m1 = muv[1];
    float z[8] = {m0[0], m0[1], m0[2], m0[3], m1[0], m1[1], m1[2], m1[3]};
    const f32x4* Lv = reinterpret_cast<const f32x4*>(L + (size_t)a * 64);
    #pragma unroll
    for (int i = 0; i < 4; ++i) {
        const f32x4 r0 = Lv[i * 2];
        #pragma unroll
        for (int j = 0; j <= i; ++j) z[i] += r0[j] * e[j];
    }
    #pragma unroll
    for (int i = 4; i < 8; ++i) {
        const f32x4 r0 = Lv[i * 2];
        const f32x4 r1 = Lv[i * 2 + 1];
        const float r[8] = {r0[0], r0[1], r0[2], r0[3], r1[0], r1[1], r1[2], r1[3]};
        #pragma unroll
        for (int j = 0; j <= i; ++j) z[i] += r[j] * e[j];
    }
    f32x4* outv = reinterpret_cast<f32x4*>(out + (size_t)b * 8);
    f32x4 o0 = {z[0], z[1], z[2], z[3]};
    f32x4 o1 = {z[4], z[5], z[6], z[7]};
    outv[0] = o0;
    outv[1] = o1;
}

extern "C" void kernel_launch(void* const* d_in, const int* in_sizes, int n_in,
                              void* d_out, int out_size, void* d_ws, size_t ws_size,
                              hipStream_t stream) {
    const int*   ann = (const int*)d_in[0];    // annotator [B]
    const float* mu  = (const float*)d_in[1];  // posterior_mu [A,8]
    const float* L   = (const float*)d_in[2];  // posterior_covtril [A,8,8]
    const float* eps = (const float*)d_in[3];  // eps [B,8]
    float* out = (float*)d_out;

    const int B = in_sizes[0];
    const int A = in_sizes[1] / 8;

    const size_t rec_bytes = (size_t)A * 64 * sizeof(_Float16);  // 8 MiB
    if (ws_size >= rec_bytes) {
        _Float16* rec = (_Float16*)d_ws;
        pack_kernel<<<(A + 255) / 256, 256, 0, stream>>>(mu, L, rec, A);
        const int blocks = (B + 127) / 128;   // 1 wave x 128 rows per block
        lv_lds<<<blocks, 64, 0, stream>>>(ann, rec, eps, out, B);
    } else {
        const int blocks = (B + 255) / 256;
        lv_kernel_f32<<<blocks, 256, 0, stream>>>(ann, mu, L, eps, out, B);
    }
}

// Round 6
// 51.584 us; speedup vs baseline: 1.1266x; 1.1266x over previous
//
#include <hip/hip_runtime.h>
#include <hip/hip_bf16.h>
#include <hip/hip_fp16.h>

// z[b,i] = mu[a_b,i] + sum_{j<=i} L[a_b,i,j] * eps[b,j]
// B = 1048576, A = 65536, D = 8
//
// Round-6: minimize 64B lines touched per row. Two packed fp16 tables:
//   SL  [A,32 halfs=64B]: strict-lower tril (28) + pad(4) -> 1 line/row
//   MD  [A,16 halfs=32B]: mu(8) + diag(8)               -> 1 line/row
// Direct VGPR loads (no LDS/DMA), 256-thread blocks, nontemporal streams.

typedef float    f32x4 __attribute__((ext_vector_type(4)));
typedef _Float16 f16x8 __attribute__((ext_vector_type(8)));

// strict-lower flat s(i,j)=i(i-1)/2+j -> L flat index i*8+j
__device__ __constant__ const int SL_SRC[28] = {
    8,                          // i=1
    16,17,                      // i=2
    24,25,26,                   // i=3
    32,33,34,35,                // i=4
    40,41,42,43,44,             // i=5
    48,49,50,51,52,53,          // i=6
    56,57,58,59,60,61,62        // i=7
};
__device__ __constant__ const int DIAG_SRC[8] = {0,9,18,27,36,45,54,63};

__global__ __launch_bounds__(256) void pack_kernel(
    const float* __restrict__ mu,   // [A,8]
    const float* __restrict__ L,    // [A,64]
    _Float16* __restrict__ sl,      // [A,32] halfs (64B rec)
    _Float16* __restrict__ md,      // [A,16] halfs (32B rec)
    int A)
{
    int a = blockIdx.x * blockDim.x + threadIdx.x;
    if (a >= A) return;

    const f32x4* muv = reinterpret_cast<const f32x4*>(mu + (size_t)a * 8);
    const f32x4* Lv  = reinterpret_cast<const f32x4*>(L + (size_t)a * 64);
    f32x4 m0 = __builtin_nontemporal_load(muv);
    f32x4 m1 = __builtin_nontemporal_load(muv + 1);
    f32x4 r[16];
    #pragma unroll
    for (int k = 0; k < 16; ++k) r[k] = __builtin_nontemporal_load(Lv + k);

    f16x8 slc[4];
    #pragma unroll
    for (int k = 0; k < 28; ++k) {
        const int f = SL_SRC[k];
        slc[k >> 3][k & 7] = (_Float16)r[f >> 2][f & 3];
    }
    #pragma unroll
    for (int k = 28; k < 32; ++k) slc[k >> 3][k & 7] = (_Float16)0.f;

    f16x8 md0, md1;
    #pragma unroll
    for (int j = 0; j < 4; ++j) { md0[j] = (_Float16)m0[j]; md0[4+j] = (_Float16)m1[j]; }
    #pragma unroll
    for (int j = 0; j < 8; ++j) {
        const int f = DIAG_SRC[j];
        md1[j] = (_Float16)r[f >> 2][f & 3];
    }

    f16x8* so = reinterpret_cast<f16x8*>(sl + (size_t)a * 32);
    #pragma unroll
    for (int c = 0; c < 4; ++c) __builtin_nontemporal_store(slc[c], so + c);
    f16x8* mo = reinterpret_cast<f16x8*>(md + (size_t)a * 16);
    __builtin_nontemporal_store(md0, mo);
    __builtin_nontemporal_store(md1, mo + 1);
}

__global__ __launch_bounds__(256) void lv_main(
    const int* __restrict__ ann,        // [B]
    const _Float16* __restrict__ sl,    // [A,32]
    const _Float16* __restrict__ md,    // [A,16]
    const float* __restrict__ eps,      // [B,8]
    float* __restrict__ out,            // [B,8]
    int B)
{
    int b = blockIdx.x * blockDim.x + threadIdx.x;
    if (b >= B) return;

    const int a = __builtin_nontemporal_load(ann + b);

    // streams (independent of a) — issue early
    const f32x4* epsv = reinterpret_cast<const f32x4*>(eps + (size_t)b * 8);
    const f32x4 e0 = __builtin_nontemporal_load(epsv);
    const f32x4 e1 = __builtin_nontemporal_load(epsv + 1);

    // gathers: 2 lines/row total (SL one line, MD half-line)
    const f16x8* slp = reinterpret_cast<const f16x8*>(sl + (size_t)a * 32);
    const f16x8 c0 = slp[0], c1 = slp[1], c2 = slp[2], c3 = slp[3];
    const f16x8* mdp = reinterpret_cast<const f16x8*>(md + (size_t)a * 16);
    const f16x8 md0 = mdp[0], md1 = mdp[1];

    const float e[8] = {e0[0], e0[1], e0[2], e0[3], e1[0], e1[1], e1[2], e1[3]};

    // z[i] = mu[i] + diag[i]*e[i] + sum_{j<i} sl[s(i,j)]*e[j]
    float z[8];
    #pragma unroll
    for (int i = 0; i < 8; ++i) z[i] = (float)md0[i] + (float)md1[i] * e[i];

    const f16x8 slc[4] = {c0, c1, c2, c3};
    #pragma unroll
    for (int i = 1; i < 8; ++i) {
        const int base = i * (i - 1) / 2;
        #pragma unroll
        for (int j = 0; j < i; ++j) {
            const int s = base + j;
            z[i] += (float)slc[s >> 3][s & 7] * e[j];
        }
    }

    f32x4* outv = reinterpret_cast<f32x4*>(out + (size_t)b * 8);
    f32x4 o0 = {z[0], z[1], z[2], z[3]};
    f32x4 o1 = {z[4], z[5], z[6], z[7]};
    __builtin_nontemporal_store(o0, outv);
    __builtin_nontemporal_store(o1, outv + 1);
}

// ---- fallback: fp32 direct (if ws too small) ----
__global__ __launch_bounds__(256) void lv_kernel_f32(
    const int* __restrict__ ann,
    const float* __restrict__ mu,
    const float* __restrict__ L,
    const float* __restrict__ eps,
    float* __restrict__ out,
    int B)
{
    int b = blockIdx.x * blockDim.x + threadIdx.x;
    if (b >= B) return;
    const int a = ann[b];
    const f32x4* epsv = reinterpret_cast<const f32x4*>(eps + (size_t)b * 8);
    const f32x4 e0 = epsv[0];
    const f32x4 e1 = epsv[1];
    const float e[8] = {e0[0], e0[1], e0[2], e0[3], e1[0], e1[1], e1[2], e1[3]};
    const f32x4* muv = reinterpret_cast<const f32x4*>(mu + (size_t)a * 8);
    const f32x4 m0 = muv[0];
    const f32x4 m1 = muv[1];
    float z[8] = {m0[0], m0[1], m0[2], m0[3], m1[0], m1[1], m1[2], m1[3]};
    const f32x4* Lv = reinterpret_cast<const f32x4*>(L + (size_t)a * 64);
    #pragma unroll
    for (int i = 0; i < 4; ++i) {
        const f32x4 r0 = Lv[i * 2];
        #pragma unroll
        for (int j = 0; j <= i; ++j) z[i] += r0[j] * e[j];
    }
    #pragma unroll
    for (int i = 4; i < 8; ++i) {
        const f32x4 r0 = Lv[i * 2];
        const f32x4 r1 = Lv[i * 2 + 1];
        const float rr[8] = {r0[0], r0[1], r0[2], r0[3], r1[0], r1[1], r1[2], r1[3]};
        #pragma unroll
        for (int j = 0; j <= i; ++j) z[i] += rr[j] * e[j];
    }
    f32x4* outv = reinterpret_cast<f32x4*>(out + (size_t)b * 8);
    f32x4 o0 = {z[0], z[1], z[2], z[3]};
    f32x4 o1 = {z[4], z[5], z[6], z[7]};
    outv[0] = o0;
    outv[1] = o1;
}

extern "C" void kernel_launch(void* const* d_in, const int* in_sizes, int n_in,
                              void* d_out, int out_size, void* d_ws, size_t ws_size,
                              hipStream_t stream) {
    const int*   ann = (const int*)d_in[0];    // annotator [B]
    const float* mu  = (const float*)d_in[1];  // posterior_mu [A,8]
    const float* L   = (const float*)d_in[2];  // posterior_covtril [A,8,8]
    const float* eps = (const float*)d_in[3];  // eps [B,8]
    float* out = (float*)d_out;

    const int B = in_sizes[0];
    const int A = in_sizes[1] / 8;

    const size_t sl_bytes = (size_t)A * 32 * sizeof(_Float16);  // 4 MiB
    const size_t md_bytes = (size_t)A * 16 * sizeof(_Float16);  // 2 MiB
    if (ws_size >= sl_bytes + md_bytes) {
        _Float16* sl = (_Float16*)d_ws;
        _Float16* md = (_Float16*)((char*)d_ws + sl_bytes);
        pack_kernel<<<(A + 255) / 256, 256, 0, stream>>>(mu, L, sl, md, A);
        lv_main<<<(B + 255) / 256, 256, 0, stream>>>(ann, sl, md, eps, out, B);
    } else {
        lv_kernel_f32<<<(B + 255) / 256, 256, 0, stream>>>(ann, mu, L, eps, out, B);
    }
}

// Round 7
// 50.006 us; speedup vs baseline: 1.1621x; 1.0316x over previous
//
#include <hip/hip_runtime.h>
#include <hip/hip_bf16.h>
#include <hip/hip_fp16.h>

// z[b,i] = mu[a_b,i] + sum_{j<=i} L[a_b,i,j] * eps[b,j]
// B = 1048576, A = 65536, D = 8
//
// Round-7: latency-bound theory. 4 rows/thread, phase-batched loads
// (4 ann -> 24 record gathers -> 8 eps) to multiply misses in flight.
// Single packed fp16 record, stride 96B (always exactly 2 lines):
//   h[0..27]  strict-lower L  (s(i,j) = i(i-1)/2 + j)
//   h[28..35] mu[0..7]
//   h[36..43] diag[0..7]
//   h[44..47] pad

typedef float    f32x4 __attribute__((ext_vector_type(4)));
typedef _Float16 f16x8 __attribute__((ext_vector_type(8)));

__device__ __constant__ const int SL_SRC[28] = {
    8, 16,17, 24,25,26, 32,33,34,35, 40,41,42,43,44,
    48,49,50,51,52,53, 56,57,58,59,60,61,62
};
__device__ __constant__ const int DIAG_SRC[8] = {0,9,18,27,36,45,54,63};

__global__ __launch_bounds__(256) void pack_kernel(
    const float* __restrict__ mu,   // [A,8]
    const float* __restrict__ L,    // [A,64]
    _Float16* __restrict__ rec,     // [A,48] halfs (96B rec)
    int A)
{
    int a = blockIdx.x * blockDim.x + threadIdx.x;
    if (a >= A) return;

    const f32x4* muv = reinterpret_cast<const f32x4*>(mu + (size_t)a * 8);
    const f32x4* Lv  = reinterpret_cast<const f32x4*>(L + (size_t)a * 64);
    f32x4 m0 = __builtin_nontemporal_load(muv);
    f32x4 m1 = __builtin_nontemporal_load(muv + 1);
    f32x4 r[16];
    #pragma unroll
    for (int k = 0; k < 16; ++k) r[k] = __builtin_nontemporal_load(Lv + k);

    f16x8 ch[6];
    #pragma unroll
    for (int k = 0; k < 28; ++k) {
        const int f = SL_SRC[k];
        ch[k >> 3][k & 7] = (_Float16)r[f >> 2][f & 3];
    }
    #pragma unroll
    for (int i = 0; i < 8; ++i) {
        const int k = 28 + i;
        const float v = (i < 4) ? m0[i] : m1[i - 4];
        ch[k >> 3][k & 7] = (_Float16)v;
    }
    #pragma unroll
    for (int i = 0; i < 8; ++i) {
        const int k = 36 + i;
        const int f = DIAG_SRC[i];
        ch[k >> 3][k & 7] = (_Float16)r[f >> 2][f & 3];
    }
    #pragma unroll
    for (int k = 44; k < 48; ++k) ch[k >> 3][k & 7] = (_Float16)0.f;

    f16x8* o = reinterpret_cast<f16x8*>(rec + (size_t)a * 48);
    #pragma unroll
    for (int c = 0; c < 6; ++c) __builtin_nontemporal_store(ch[c], o + c);
}

#define ROWS 4

__global__ __launch_bounds__(256) void lv_main(
    const int* __restrict__ ann,        // [B]
    const _Float16* __restrict__ rec,   // [A,48]
    const float* __restrict__ eps,      // [B,8]
    float* __restrict__ out,            // [B,8]
    int B)
{
    const int tid = threadIdx.x;
    const long base = (long)blockIdx.x * (256 * ROWS);

    // phase 1: 4 independent annotator loads
    long row[ROWS];
    int a[ROWS];
    #pragma unroll
    for (int k = 0; k < ROWS; ++k) {
        row[k] = base + k * 256 + tid;          // coalesced per phase
        a[k] = (row[k] < (long)B) ? __builtin_nontemporal_load(ann + row[k]) : 0;
    }

    // phase 2: 24 scattered record-chunk gathers, all independent
    f16x8 ch[ROWS][6];
    #pragma unroll
    for (int k = 0; k < ROWS; ++k) {
        const f16x8* rp = reinterpret_cast<const f16x8*>(rec + (size_t)a[k] * 48);
        #pragma unroll
        for (int c = 0; c < 6; ++c) ch[k][c] = rp[c];
    }

    // phase 3: 8 streaming eps loads
    f32x4 ev0[ROWS], ev1[ROWS];
    #pragma unroll
    for (int k = 0; k < ROWS; ++k) {
        const long rc = (row[k] < (long)B) ? row[k] : 0;
        const f32x4* ep = reinterpret_cast<const f32x4*>(eps + (size_t)rc * 8);
        ev0[k] = __builtin_nontemporal_load(ep);
        ev1[k] = __builtin_nontemporal_load(ep + 1);
    }

    // phase 4: compute + store per row
    #pragma unroll
    for (int k = 0; k < ROWS; ++k) {
        if (row[k] >= (long)B) continue;
        const float e[8] = {ev0[k][0], ev0[k][1], ev0[k][2], ev0[k][3],
                            ev1[k][0], ev1[k][1], ev1[k][2], ev1[k][3]};
        float z[8];
        // z[i] = mu[i] + diag[i]*e[i]
        #pragma unroll
        for (int i = 0; i < 8; ++i) {
            const int km = 28 + i, kd = 36 + i;
            z[i] = (float)ch[k][km >> 3][km & 7]
                 + (float)ch[k][kd >> 3][kd & 7] * e[i];
        }
        // strict-lower
        #pragma unroll
        for (int i = 1; i < 8; ++i) {
            const int sb = i * (i - 1) / 2;
            #pragma unroll
            for (int j = 0; j < i; ++j) {
                const int s = sb + j;
                z[i] += (float)ch[k][s >> 3][s & 7] * e[j];
            }
        }
        f32x4* outv = reinterpret_cast<f32x4*>(out + (size_t)row[k] * 8);
        f32x4 o0 = {z[0], z[1], z[2], z[3]};
        f32x4 o1 = {z[4], z[5], z[6], z[7]};
        __builtin_nontemporal_store(o0, outv);
        __builtin_nontemporal_store(o1, outv + 1);
    }
}

// ---- fallback: fp32 direct (if ws too small) ----
__global__ __launch_bounds__(256) void lv_kernel_f32(
    const int* __restrict__ ann,
    const float* __restrict__ mu,
    const float* __restrict__ L,
    const float* __restrict__ eps,
    float* __restrict__ out,
    int B)
{
    int b = blockIdx.x * blockDim.x + threadIdx.x;
    if (b >= B) return;
    const int a = ann[b];
    const f32x4* epsv = reinterpret_cast<const f32x4*>(eps + (size_t)b * 8);
    const f32x4 e0 = epsv[0];
    const f32x4 e1 = epsv[1];
    const float e[8] = {e0[0], e0[1], e0[2], e0[3], e1[0], e1[1], e1[2], e1[3]};
    const f32x4* muv = reinterpret_cast<const f32x4*>(mu + (size_t)a * 8);
    const f32x4 m0 = muv[0];
    const f32x4 m1 = muv[1];
    float z[8] = {m0[0], m0[1], m0[2], m0[3], m1[0], m1[1], m1[2], m1[3]};
    const f32x4* Lv = reinterpret_cast<const f32x4*>(L + (size_t)a * 64);
    #pragma unroll
    for (int i = 0; i < 4; ++i) {
        const f32x4 r0 = Lv[i * 2];
        #pragma unroll
        for (int j = 0; j <= i; ++j) z[i] += r0[j] * e[j];
    }
    #pragma unroll
    for (int i = 4; i < 8; ++i) {
        const f32x4 r0 = Lv[i * 2];
        const f32x4 r1 = Lv[i * 2 + 1];
        const float rr[8] = {r0[0], r0[1], r0[2], r0[3], r1[0], r1[1], r1[2], r1[3]};
        #pragma unroll
        for (int j = 0; j <= i; ++j) z[i] += rr[j] * e[j];
    }
    f32x4* outv = reinterpret_cast<f32x4*>(out + (size_t)b * 8);
    f32x4 o0 = {z[0], z[1], z[2], z[3]};
    f32x4 o1 = {z[4], z[5], z[6], z[7]};
    outv[0] = o0;
    outv[1] = o1;
}

extern "C" void kernel_launch(void* const* d_in, const int* in_sizes, int n_in,
                              void* d_out, int out_size, void* d_ws, size_t ws_size,
                              hipStream_t stream) {
    const int*   ann = (const int*)d_in[0];    // annotator [B]
    const float* mu  = (const float*)d_in[1];  // posterior_mu [A,8]
    const float* L   = (const float*)d_in[2];  // posterior_covtril [A,8,8]
    const float* eps = (const float*)d_in[3];  // eps [B,8]
    float* out = (float*)d_out;

    const int B = in_sizes[0];
    const int A = in_sizes[1] / 8;

    const size_t rec_bytes = (size_t)A * 48 * sizeof(_Float16);  // 6 MiB
    if (ws_size >= rec_bytes) {
        _Float16* rec = (_Float16*)d_ws;
        pack_kernel<<<(A + 255) / 256, 256, 0, stream>>>(mu, L, rec, A);
        const int rows_per_block = 256 * ROWS;
        const int blocks = (B + rows_per_block - 1) / rows_per_block;
        lv_main<<<blocks, 256, 0, stream>>>(ann, rec, eps, out, B);
    } else {
        lv_kernel_f32<<<(B + 255) / 256, 256, 0, stream>>>(ann, mu, L, eps, out, B);
    }
}